// Round 11
// baseline (547.706 us; speedup 1.0000x reference)
//
#include <hip/hip_runtime.h>
#include <math.h>

#define NPTS  4096
#define KNN   20
#define BLK   256
#define SPLIT 8
#define CHUNK (NPTS / SPLIT)   // 512 candidates per lane
#define PPB   (BLK / SPLIT)    // 32 points per block
#define BUF   6                // per-lane pending cap between flushes
#define CAP   (SPLIT * BUF)    // group queue capacity = 48

// ---------- pass 1: stage (x,y,z,xx) as float4 in workspace ----------
__global__ __launch_bounds__(256) void stage_kernel(
    const float* __restrict__ x, float4* __restrict__ ws)
{
    const int i = blockIdx.x * 256 + threadIdx.x;   // over B*NPTS
    const int b = i >> 12;
    const int m = i & (NPTS - 1);
    const float* xb = x + (size_t)b * 3 * NPTS;
    {
        #pragma clang fp contract(off)
        const float a = xb[m];
        const float c = xb[NPTS + m];
        const float e = xb[2 * NPTS + m];
        // frozen np rounding: xx = ((a*a)+(c*c))+(e*e), per-op rounded, NO fma
        const float pa = a * a;
        const float pc = c * c;
        const float pe = e * e;
        const float s01 = pa + pc;
        const float xx = s01 + pe;
        ws[i] = make_float4(a, c, e, xx);
    }
}

__global__ __launch_bounds__(BLK, 4) void gap_layer_kernel(
    const float4* __restrict__ xs4,   // staged (x,y,z,xx), B*NPTS
    const float* __restrict__ w1,
    const float* __restrict__ g1, const float* __restrict__ be1,
    const float* __restrict__ mu1, const float* __restrict__ va1,
    const float* __restrict__ w2, const float* __restrict__ b2,
    const float* __restrict__ g2, const float* __restrict__ be2,
    const float* __restrict__ mu2, const float* __restrict__ va2,
    const float* __restrict__ w3, const float* __restrict__ b3,
    const float* __restrict__ g3, const float* __restrict__ be3,
    const float* __restrict__ mu3, const float* __restrict__ va3,
    float* __restrict__ out_ret,   // (B, N, 16) flat
    float* __restrict__ out_edge)  // (B, 16, N, KNN) flat
{
    __shared__ unsigned long long qbuf[PPB][CAP];   // 32*48*8 = 12 KB
    __shared__ int   gcnt[PPB];
    __shared__ float4 wA[16], wE[16];
    __shared__ float  w3s[16];
    __shared__ float  fb3s;

    const int tid = threadIdx.x;
    const int p   = tid >> 3;      // local point 0..31 (8-lane group)
    const int c   = tid & 7;       // lane-in-group
    const int b     = blockIdx.x >> 7;            // 8 batches * 128 blocks
    const int nbase = (blockIdx.x & 127) * PPB;
    const int n     = nbase + p;

    if (tid < 16) {
        const int o = tid;
        float s1 = g1[o] * rsqrtf(va1[o] + 1e-5f);
        float fb1o = -mu1[o] * s1 + be1[o];
        wA[o] = make_float4(w1[o*3+0]*s1, w1[o*3+1]*s1, w1[o*3+2]*s1, fb1o);
        float s2 = g2[o] * rsqrtf(va2[o] + 1e-5f);
        float fb2o = (b2[o] - mu2[o]) * s2 + be2[o];
        wE[o] = make_float4(w2[o*3+0]*s2, w2[o*3+1]*s2, w2[o*3+2]*s2, fb2o);
        float s3 = g3[0] * rsqrtf(va3[0] + 1e-5f);
        w3s[o] = w3[o] * s3;
        if (o == 0) fb3s = (b3[0] - mu3[0]) * s3 + be3[0];
    }
    if (tid < PPB) gcnt[tid] = 0;
    __syncthreads();

    const float4* xb4 = xs4 + (size_t)b * NPTS;
    const float4 me = xb4[n];
    const float xnf = me.x, ynf = me.y, znf = me.z, xxn = me.w;

    // ---- group-shared exact top-20 as sortable u64 keys:
    //      key = (mono(v) << 32) | (4095 - m); key desc == (v desc, m asc).
    //      All 8 lanes hold identical copies (lockstep). ----
    unsigned long long bk[KNN];
    #pragma unroll
    for (int j = 0; j < KNN; ++j) bk[j] = 0ull;
    float thr = -3.402823466e38f;
    int cnt = 0;

    auto do_flush = [&]() {
        const int total = *(volatile int*)&gcnt[p];     // group-uniform
        volatile unsigned long long* qq = &qbuf[p][0];
        for (int i = 0; i < total; ++i) {
            const unsigned long long item = qq[i];
            bool cc[KNN];
            #pragma unroll
            for (int j = 0; j < KNN; ++j) cc[j] = item > bk[j];
            #pragma unroll
            for (int j = KNN - 1; j >= 1; --j)
                bk[j] = cc[j] ? (cc[j - 1] ? bk[j - 1] : item) : bk[j];
            if (cc[0]) bk[0] = item;
        }
        if (c == 0) *(volatile int*)&gcnt[p] = 0;
        cnt = 0;
        const unsigned s19 = (unsigned)(bk[KNN - 1] >> 32);
        thr = (s19 == 0u) ? -3.402823466e38f
            : __uint_as_float((s19 & 0x80000000u) ? (s19 ^ 0x80000000u) : ~s19);
    };

    #pragma unroll 2
    for (int t = 0; t < CHUNK; ++t) {
        const int m = (t << 3) | c;
        const float4 q4 = xb4[m];
        float v;
        {
            #pragma clang fp contract(off)
            const float p0    = xnf * q4.x;
            const float f1    = __builtin_fmaf(ynf, q4.y, p0);
            const float inner = __builtin_fmaf(znf, q4.z, f1);
            const float two_i = inner + inner;
            const float tt    = two_i - q4.w;
            v = tt - xxn;
        }
        if (v >= thr) {
            const unsigned fb = __float_as_uint(v);
            const unsigned s  = fb ^ (unsigned)(((int)fb >> 31) | 0x80000000);
            const unsigned long long key =
                ((unsigned long long)s << 32) | (unsigned)(NPTS - 1 - m);
            const int pos = atomicAdd(&gcnt[p], 1);
            *(volatile unsigned long long*)&qbuf[p][pos] = key;
            ++cnt;
        }
        if (__any(cnt >= BUF)) do_flush();
    }
    do_flush();   // final drain

    // ---- lane's ranks: r = c + 8j (j=2 only for c<4) ----
    float d0[3], d1[3], d2[3];
    {
        int mj[3];
        #pragma unroll
        for (int j = 0; j < 3; ++j) {
            const int r = c + 8 * j;
            const int rr = (r < KNN) ? r : 0;
            mj[j] = NPTS - 1 - (int)(unsigned)(bk[rr] & 0xFFFFFFFFull);
        }
        #pragma unroll
        for (int j = 0; j < 3; ++j) {
            const float4 q4 = xb4[mj[j]];
            d0[j] = xnf - q4.x;
            d1[j] = ynf - q4.y;
            d2[j] = znf - q4.z;
        }
    }
    const bool has3 = (c < 4);

    // ---- attention logits + edge_feature output ----
    float sacc[3] = {0.f, 0.f, 0.f}, nacc[3] = {0.f, 0.f, 0.f};
    const float fb3 = fb3s;
    for (int o = 0; o < 16; ++o) {
        const float4 wa = wA[o];
        const float4 we = wE[o];
        const float w3o = w3s[o];
        const size_t ebase = (((size_t)b * 16 + o) * NPTS + n) * KNN + c;
        #pragma unroll
        for (int j = 0; j < 3; ++j) {
            float f1 = fmaf(d2[j], wa.z, fmaf(d1[j], wa.y, fmaf(d0[j], wa.x, wa.w)));
            f1 = fmaxf(f1, 0.f);
            sacc[j] = fmaf(f1, w3o, sacc[j]);
            float ee = fmaf(d2[j], we.z, fmaf(d1[j], we.y, fmaf(d0[j], we.x, we.w)));
            ee = fmaxf(ee, 0.f);
            nacc[j] = fmaf(ee, w3o, nacc[j]);
            if (j < 2) out_edge[ebase + 8 * j] = ee;
            else if (has3) out_edge[ebase + 16] = ee;
        }
    }

    // ---- leaky_relu + softmax over k (8-lane group = one point) ----
    float att[3];
    float mx = -3.402823466e38f;
    #pragma unroll
    for (int j = 0; j < 3; ++j) {
        float l = fmaxf(sacc[j] + fb3, 0.f) + fmaxf(nacc[j] + fb3, 0.f);
        l = (l >= 0.f) ? l : 0.01f * l;
        att[j] = l;
        if (j < 2 || has3) mx = fmaxf(mx, l);
    }
    mx = fmaxf(mx, __shfl_xor(mx, 1));
    mx = fmaxf(mx, __shfl_xor(mx, 2));
    mx = fmaxf(mx, __shfl_xor(mx, 4));
    float sum = 0.f;
    #pragma unroll
    for (int j = 0; j < 3; ++j) {
        float e = expf(att[j] - mx);
        if (j == 2 && !has3) e = 0.f;
        att[j] = e;
        sum += e;
    }
    sum += __shfl_xor(sum, 1);
    sum += __shfl_xor(sum, 2);
    sum += __shfl_xor(sum, 4);
    const float inv = 1.f / sum;
    #pragma unroll
    for (int j = 0; j < 3; ++j) att[j] *= inv;

    // ---- weighted edge sum (recompute edge), group-reduce, elu, write ret ----
    float val[16];
    for (int o = 0; o < 16; ++o) {
        const float4 we = wE[o];
        float v = 0.f;
        #pragma unroll
        for (int j = 0; j < 3; ++j) {
            float ee = fmaf(d2[j], we.z, fmaf(d1[j], we.y, fmaf(d0[j], we.x, we.w)));
            ee = fmaxf(ee, 0.f);
            v = fmaf(att[j], ee, v);
        }
        val[o] = v;
    }
    #pragma unroll
    for (int o = 0; o < 16; ++o) {
        val[o] += __shfl_xor(val[o], 1);
        val[o] += __shfl_xor(val[o], 2);
        val[o] += __shfl_xor(val[o], 4);
    }
    const size_t rbase = ((size_t)b * NPTS + n) * 16;
    #pragma unroll
    for (int oi = 0; oi < 2; ++oi) {
        const int o = 2 * c + oi;
        const float vv = val[o];
        out_ret[rbase + o] = (vv > 0.f) ? vv : expm1f(vv);
    }
}

extern "C" void kernel_launch(void* const* d_in, const int* in_sizes, int n_in,
                              void* d_out, int out_size, void* d_ws, size_t ws_size,
                              hipStream_t stream) {
    (void)n_in; (void)out_size; (void)ws_size;
    const float* x   = (const float*)d_in[0];
    const float* w1  = (const float*)d_in[1];
    const float* g1  = (const float*)d_in[2];
    const float* be1 = (const float*)d_in[3];
    const float* mu1 = (const float*)d_in[4];
    const float* va1 = (const float*)d_in[5];
    const float* w2  = (const float*)d_in[6];
    const float* b2  = (const float*)d_in[7];
    const float* g2  = (const float*)d_in[8];
    const float* be2 = (const float*)d_in[9];
    const float* mu2 = (const float*)d_in[10];
    const float* va2 = (const float*)d_in[11];
    const float* w3  = (const float*)d_in[12];
    const float* b3  = (const float*)d_in[13];
    const float* g3  = (const float*)d_in[14];
    const float* be3 = (const float*)d_in[15];
    const float* mu3 = (const float*)d_in[16];
    const float* va3 = (const float*)d_in[17];

    const int B = in_sizes[0] / (3 * NPTS);   // = 8
    float* out_ret  = (float*)d_out;                          // B*N*16
    float* out_edge = out_ret + (size_t)B * NPTS * 16;        // B*16*N*K

    float4* xs4 = (float4*)d_ws;              // B*NPTS float4 = 512 KB

    stage_kernel<<<B * NPTS / 256, 256, 0, stream>>>(x, xs4);

    const int grid = B * (NPTS / PPB);        // 8 * 128 = 1024 blocks
    gap_layer_kernel<<<grid, BLK, 0, stream>>>(
        xs4, w1, g1, be1, mu1, va1, w2, b2, g2, be2, mu2, va2,
        w3, b3, g3, be3, mu3, va3, out_ret, out_edge);
}

// Round 12
// 383.008 us; speedup vs baseline: 1.4300x; 1.4300x over previous
//
#include <hip/hip_runtime.h>
#include <math.h>

#define NPTS  4096
#define KNN   20
#define BLK   256
#define SPLIT 8
#define CHUNK (NPTS / SPLIT)   // 512 candidates per lane
#define PPB   (BLK / SPLIT)    // 32 points per block
#define BUF   4
#define NEGBIG -3.402823466e38f

// ---------- pass 1: stage (x,y,z,xx) as float4 in workspace ----------
__global__ __launch_bounds__(256) void stage_kernel(
    const float* __restrict__ x, float4* __restrict__ ws)
{
    const int i = blockIdx.x * 256 + threadIdx.x;   // over B*NPTS
    const int b = i >> 12;
    const int m = i & (NPTS - 1);
    const float* xb = x + (size_t)b * 3 * NPTS;
    {
        #pragma clang fp contract(off)
        const float a = xb[m];
        const float c = xb[NPTS + m];
        const float e = xb[2 * NPTS + m];
        // frozen np rounding: xx = ((a*a)+(c*c))+(e*e), per-op rounded, NO fma
        const float pa = a * a;
        const float pc = c * c;
        const float pe = e * e;
        const float s01 = pa + pc;
        const float xx = s01 + pe;
        ws[i] = make_float4(a, c, e, xx);
    }
}

// full stable sorted-insert body (strict >; equal keys keep earlier m)
#define INSERT_BODY(VV, II)                                              \
    {                                                                    \
        bool cc_[KNN];                                                   \
        _Pragma("unroll")                                                \
        for (int j_ = 0; j_ < KNN; ++j_) cc_[j_] = (VV) > bv[j_];        \
        _Pragma("unroll")                                                \
        for (int j_ = KNN - 1; j_ >= 1; --j_) {                          \
            bv[j_] = cc_[j_] ? (cc_[j_ - 1] ? bv[j_ - 1] : (VV)) : bv[j_]; \
            bi[j_] = cc_[j_] ? (cc_[j_ - 1] ? bi[j_ - 1] : (II)) : bi[j_]; \
        }                                                                \
        if (cc_[0]) { bv[0] = (VV); bi[0] = (II); }                      \
    }

__global__ __launch_bounds__(BLK, 4) void gap_layer_kernel(
    const float4* __restrict__ xs4,   // staged (x,y,z,xx), B*NPTS
    const float* __restrict__ w1,
    const float* __restrict__ g1, const float* __restrict__ be1,
    const float* __restrict__ mu1, const float* __restrict__ va1,
    const float* __restrict__ w2, const float* __restrict__ b2,
    const float* __restrict__ g2, const float* __restrict__ be2,
    const float* __restrict__ mu2, const float* __restrict__ va2,
    const float* __restrict__ w3, const float* __restrict__ b3,
    const float* __restrict__ g3, const float* __restrict__ be3,
    const float* __restrict__ mu3, const float* __restrict__ va3,
    float* __restrict__ out_ret,   // (B, N, 16) flat
    float* __restrict__ out_edge)  // (B, 16, N, KNN) flat
{
    __shared__ float          sv[BLK * KNN];      // 20480 B
    __shared__ unsigned short si[BLK * KNN];      // 10240 B
    __shared__ unsigned       thrsh[PPB];
    __shared__ float4 wA[16], wE[16];
    __shared__ float  w3s[16];
    __shared__ float  fb3s;

    const int tid = threadIdx.x;
    const int p   = tid >> 3;      // local point 0..31 (8-lane group)
    const int c   = tid & 7;       // chunk / lane-in-group
    const int b     = blockIdx.x >> 7;            // 8 batches * 128 blocks
    const int nbase = (blockIdx.x & 127) * PPB;
    const int n     = nbase + p;

    if (tid < 16) {
        const int o = tid;
        float s1 = g1[o] * rsqrtf(va1[o] + 1e-5f);
        float fb1o = -mu1[o] * s1 + be1[o];
        wA[o] = make_float4(w1[o*3+0]*s1, w1[o*3+1]*s1, w1[o*3+2]*s1, fb1o);
        float s2 = g2[o] * rsqrtf(va2[o] + 1e-5f);
        float fb2o = (b2[o] - mu2[o]) * s2 + be2[o];
        wE[o] = make_float4(w2[o*3+0]*s2, w2[o*3+1]*s2, w2[o*3+2]*s2, fb2o);
        float s3 = g3[0] * rsqrtf(va3[0] + 1e-5f);
        w3s[o] = w3[o] * s3;
        if (o == 0) fb3s = (b3[0] - mu3[0]) * s3 + be3[0];
    }
    if (tid < PPB) thrsh[tid] = 0u;
    __syncthreads();

    const float4* xb4 = xs4 + (size_t)b * NPTS;
    const float4 me = xb4[n];
    const float xnf = me.x, ynf = me.y, znf = me.z, xxn = me.w;

    // ---- per-lane exact top-20 of chunk (pruned by shared threshold) ----
    float bv[KNN];
    int   bi[KNN];
    #pragma unroll
    for (int j = 0; j < KNN; ++j) { bv[j] = NEGBIG; bi[j] = 0; }
    float bufv[BUF];
    int   bufi[BUF];
    #pragma unroll
    for (int j = 0; j < BUF; ++j) { bufv[j] = NEGBIG; bufi[j] = 0; }
    int cnt = 0;
    float thr_f = NEGBIG;

    #pragma unroll 2
    for (int t = 0; t < CHUNK; ++t) {
        const int m = (t << 3) | c;
        const float4 q = xb4[m];
        float v;
        {
            #pragma clang fp contract(off)
            const float p0    = xnf * q.x;
            const float f1    = __builtin_fmaf(ynf, q.y, p0);
            const float inner = __builtin_fmaf(znf, q.z, f1);
            const float two_i = inner + inner;
            const float tt    = two_i - q.w;
            v = tt - xxn;
        }
        const bool pass = (v > bv[KNN - 1]) && (v >= thr_f);
        #pragma unroll
        for (int j = 0; j < BUF; ++j) {
            const bool s = pass && (cnt == j);
            bufv[j] = s ? v : bufv[j];
            bufi[j] = s ? m : bufi[j];
        }
        cnt += pass ? 1 : 0;
        if (__any(cnt >= BUF)) {
            #pragma unroll
            for (int j = 0; j < BUF; ++j) {
                INSERT_BODY(bufv[j], bufi[j]);
                bufv[j] = NEGBIG;
            }
            cnt = 0;
            // publish my 20th-best to the shared threshold; read back group max
            const unsigned fb19 = __float_as_uint(bv[KNN - 1]);
            const unsigned s19  = fb19 ^ (unsigned)(((int)fb19 >> 31) | 0x80000000u);
            atomicMax(&thrsh[p], s19);
            const unsigned tu = *(volatile unsigned*)&thrsh[p];
            thr_f = (tu == 0u) ? NEGBIG
                  : __uint_as_float((tu & 0x80000000u) ? (tu ^ 0x80000000u) : ~tu);
        }
    }
    // final drain
    #pragma unroll
    for (int j = 0; j < BUF; ++j) INSERT_BODY(bufv[j], bufi[j]);

    // ---- publish sorted sub-lists (split float / u16 arrays) ----
    {
        const int rb = tid * KNN;
        #pragma unroll
        for (int j = 0; j < KNN; ++j) {
            sv[rb + j] = bv[j];
            si[rb + j] = (unsigned short)bi[j];
        }
    }
    __syncthreads();

    // ---- 8-way tournament merge (comparator: v desc, idx asc).
    //      All 8 lanes of group p walk identically; lane c records r%8==c. ----
    const int rb0 = (p << 3) * KNN;
    float hv0 = sv[rb0 +  0*KNN]; int hi0 = si[rb0 +  0*KNN];
    float hv1 = sv[rb0 +  1*KNN]; int hi1 = si[rb0 +  1*KNN];
    float hv2 = sv[rb0 +  2*KNN]; int hi2 = si[rb0 +  2*KNN];
    float hv3 = sv[rb0 +  3*KNN]; int hi3 = si[rb0 +  3*KNN];
    float hv4 = sv[rb0 +  4*KNN]; int hi4 = si[rb0 +  4*KNN];
    float hv5 = sv[rb0 +  5*KNN]; int hi5 = si[rb0 +  5*KNN];
    float hv6 = sv[rb0 +  6*KNN]; int hi6 = si[rb0 +  6*KNN];
    float hv7 = sv[rb0 +  7*KNN]; int hi7 = si[rb0 +  7*KNN];
    int q0 = 1, q1 = 1, q2 = 1, q3 = 1, q4 = 1, q5 = 1, q6 = 1, q7 = 1;
    int mi0 = 0, mi1 = 0, mi2 = 0;

    #pragma unroll
    for (int r = 0; r < KNN; ++r) {
        // level 1
        const bool t01 = (hv1 > hv0) || (hv1 == hv0 && hi1 < hi0);
        float av = t01 ? hv1 : hv0; int ai = t01 ? hi1 : hi0; int aw = t01 ? 1 : 0;
        const bool t23 = (hv3 > hv2) || (hv3 == hv2 && hi3 < hi2);
        float bvv = t23 ? hv3 : hv2; int bii = t23 ? hi3 : hi2; int bw = t23 ? 3 : 2;
        const bool t45 = (hv5 > hv4) || (hv5 == hv4 && hi5 < hi4);
        float cv = t45 ? hv5 : hv4; int ci = t45 ? hi5 : hi4; int cw = t45 ? 5 : 4;
        const bool t67 = (hv7 > hv6) || (hv7 == hv6 && hi7 < hi6);
        float dv = t67 ? hv7 : hv6; int di = t67 ? hi7 : hi6; int dw = t67 ? 7 : 6;
        // level 2
        const bool tab = (bvv > av) || (bvv == av && bii < ai);
        float ev = tab ? bvv : av; int ei = tab ? bii : ai; int ew = tab ? bw : aw;
        const bool tcd = (dv > cv) || (dv == cv && di < ci);
        float fv = tcd ? dv : cv; int fi = tcd ? di : ci; int fw = tcd ? dw : cw;
        // level 3
        const bool tef = (fv > ev) || (fv == ev && fi < ei);
        const int wi = tef ? fi : ei;
        const int ww = tef ? fw : ew;

        // record: lane c takes ranks r = c + 8j
        if ((r & 7) == 0) { mi0 = (c == 0) ? ((r >> 3) == 0 ? wi : mi0) : mi0; }
        {
            const int j = r >> 3;
            const bool mine = (c == (r & 7));
            mi0 = (mine && j == 0) ? wi : mi0;
            mi1 = (mine && j == 1) ? wi : mi1;
            mi2 = (mine && j == 2) ? wi : mi2;
        }

        // advance the winning list
        int qw = (ww == 0) ? q0 : (ww == 1) ? q1 : (ww == 2) ? q2 : (ww == 3) ? q3
               : (ww == 4) ? q4 : (ww == 5) ? q5 : (ww == 6) ? q6 : q7;
        const int rd = (qw < KNN - 1) ? qw : (KNN - 1);
        const int ra = rb0 + ww * KNN + rd;
        float nv = sv[ra];
        const int ni = si[ra];
        nv = (qw < KNN) ? nv : NEGBIG;
        q0 += (ww == 0); q1 += (ww == 1); q2 += (ww == 2); q3 += (ww == 3);
        q4 += (ww == 4); q5 += (ww == 5); q6 += (ww == 6); q7 += (ww == 7);
        hv0 = (ww == 0) ? nv : hv0;  hi0 = (ww == 0) ? ni : hi0;
        hv1 = (ww == 1) ? nv : hv1;  hi1 = (ww == 1) ? ni : hi1;
        hv2 = (ww == 2) ? nv : hv2;  hi2 = (ww == 2) ? ni : hi2;
        hv3 = (ww == 3) ? nv : hv3;  hi3 = (ww == 3) ? ni : hi3;
        hv4 = (ww == 4) ? nv : hv4;  hi4 = (ww == 4) ? ni : hi4;
        hv5 = (ww == 5) ? nv : hv5;  hi5 = (ww == 5) ? ni : hi5;
        hv6 = (ww == 6) ? nv : hv6;  hi6 = (ww == 6) ? ni : hi6;
        hv7 = (ww == 7) ? nv : hv7;  hi7 = (ww == 7) ? ni : hi7;
    }

    // ---- edge diffs for this lane's ranks (k = c + 8j; j=2 only for c<4) ----
    const bool has3 = (c < 4);
    float d0[3], d1[3], d2[3];
    {
        const int mjs[3] = { mi0, mi1, mi2 };
        #pragma unroll
        for (int j = 0; j < 3; ++j) {
            const float4 q = xb4[mjs[j]];
            d0[j] = xnf - q.x;
            d1[j] = ynf - q.y;
            d2[j] = znf - q.z;
        }
    }

    // ---- attention logits + edge_feature output ----
    float sacc[3] = {0.f, 0.f, 0.f}, nacc[3] = {0.f, 0.f, 0.f};
    const float fb3 = fb3s;
    for (int o = 0; o < 16; ++o) {
        const float4 wa = wA[o];
        const float4 we = wE[o];
        const float w3o = w3s[o];
        const size_t ebase = (((size_t)b * 16 + o) * NPTS + n) * KNN + c;
        #pragma unroll
        for (int j = 0; j < 3; ++j) {
            float f1 = fmaf(d2[j], wa.z, fmaf(d1[j], wa.y, fmaf(d0[j], wa.x, wa.w)));
            f1 = fmaxf(f1, 0.f);
            sacc[j] = fmaf(f1, w3o, sacc[j]);
            float ee = fmaf(d2[j], we.z, fmaf(d1[j], we.y, fmaf(d0[j], we.x, we.w)));
            ee = fmaxf(ee, 0.f);
            nacc[j] = fmaf(ee, w3o, nacc[j]);
            if (j < 2) out_edge[ebase + 8 * j] = ee;
            else if (has3) out_edge[ebase + 16] = ee;
        }
    }

    // ---- leaky_relu + softmax over k (8-lane group = one point) ----
    float att[3];
    float mx = NEGBIG;
    #pragma unroll
    for (int j = 0; j < 3; ++j) {
        float l = fmaxf(sacc[j] + fb3, 0.f) + fmaxf(nacc[j] + fb3, 0.f);
        l = (l >= 0.f) ? l : 0.01f * l;
        att[j] = l;
        if (j < 2 || has3) mx = fmaxf(mx, l);
    }
    mx = fmaxf(mx, __shfl_xor(mx, 1));
    mx = fmaxf(mx, __shfl_xor(mx, 2));
    mx = fmaxf(mx, __shfl_xor(mx, 4));
    float sum = 0.f;
    #pragma unroll
    for (int j = 0; j < 3; ++j) {
        float e = expf(att[j] - mx);
        if (j == 2 && !has3) e = 0.f;
        att[j] = e;
        sum += e;
    }
    sum += __shfl_xor(sum, 1);
    sum += __shfl_xor(sum, 2);
    sum += __shfl_xor(sum, 4);
    const float inv = 1.f / sum;
    #pragma unroll
    for (int j = 0; j < 3; ++j) att[j] *= inv;

    // ---- weighted edge sum (recompute edge), group-reduce, elu, write ret ----
    float val[16];
    for (int o = 0; o < 16; ++o) {
        const float4 we = wE[o];
        float v = 0.f;
        #pragma unroll
        for (int j = 0; j < 3; ++j) {
            float ee = fmaf(d2[j], we.z, fmaf(d1[j], we.y, fmaf(d0[j], we.x, we.w)));
            ee = fmaxf(ee, 0.f);
            v = fmaf(att[j], ee, v);
        }
        val[o] = v;
    }
    #pragma unroll
    for (int o = 0; o < 16; ++o) {
        val[o] += __shfl_xor(val[o], 1);
        val[o] += __shfl_xor(val[o], 2);
        val[o] += __shfl_xor(val[o], 4);
    }
    const size_t rbase = ((size_t)b * NPTS + n) * 16;
    #pragma unroll
    for (int oi = 0; oi < 2; ++oi) {
        const int o = 2 * c + oi;
        const float vv = val[o];
        out_ret[rbase + o] = (vv > 0.f) ? vv : expm1f(vv);
    }
}

extern "C" void kernel_launch(void* const* d_in, const int* in_sizes, int n_in,
                              void* d_out, int out_size, void* d_ws, size_t ws_size,
                              hipStream_t stream) {
    (void)n_in; (void)out_size; (void)ws_size;
    const float* x   = (const float*)d_in[0];
    const float* w1  = (const float*)d_in[1];
    const float* g1  = (const float*)d_in[2];
    const float* be1 = (const float*)d_in[3];
    const float* mu1 = (const float*)d_in[4];
    const float* va1 = (const float*)d_in[5];
    const float* w2  = (const float*)d_in[6];
    const float* b2  = (const float*)d_in[7];
    const float* g2  = (const float*)d_in[8];
    const float* be2 = (const float*)d_in[9];
    const float* mu2 = (const float*)d_in[10];
    const float* va2 = (const float*)d_in[11];
    const float* w3  = (const float*)d_in[12];
    const float* b3  = (const float*)d_in[13];
    const float* g3  = (const float*)d_in[14];
    const float* be3 = (const float*)d_in[15];
    const float* mu3 = (const float*)d_in[16];
    const float* va3 = (const float*)d_in[17];

    const int B = in_sizes[0] / (3 * NPTS);   // = 8
    float* out_ret  = (float*)d_out;                          // B*N*16
    float* out_edge = out_ret + (size_t)B * NPTS * 16;        // B*16*N*K

    float4* xs4 = (float4*)d_ws;              // B*NPTS float4 = 512 KB

    stage_kernel<<<B * NPTS / 256, 256, 0, stream>>>(x, xs4);

    const int grid = B * (NPTS / PPB);        // 8 * 128 = 1024 blocks
    gap_layer_kernel<<<grid, BLK, 0, stream>>>(
        xs4, w1, g1, be1, mu1, va1, w2, b2, g2, be2, mu2, va2,
        w3, b3, g3, be3, mu3, va3, out_ret, out_edge);
}